// Round 1
// baseline (269.371 us; speedup 1.0000x reference)
//
#include <hip/hip_runtime.h>
#include <hip/hip_fp16.h>

typedef _Float16 f16;
typedef __attribute__((ext_vector_type(4))) _Float16 f16x4;
typedef __attribute__((ext_vector_type(8))) _Float16 f16x8;
typedef __attribute__((ext_vector_type(4))) float f32x4;

// ---------------------------------------------------------------------------
// Kernel 1: convert x (4M f32) and Wq/Wk/Wv/Wo (4 x 1M f32) to fp16.
// wh layout: [Wq; Wk; Wv; Wo] contiguous, each [1024][1024] row-major.
// ---------------------------------------------------------------------------
__global__ __launch_bounds__(256) void cvt_kernel(
    const float* __restrict__ x, const float* __restrict__ wq,
    const float* __restrict__ wk, const float* __restrict__ wv,
    const float* __restrict__ wo, f16* __restrict__ xh, f16* __restrict__ wh) {
  const int gid = blockIdx.x * 256 + threadIdx.x;   // 0 .. 2M-1 (float4 units)
  const int XV = (4 * 1024 * 1024) / 4;             // 1M float4 of x
  if (gid < XV) {
    float4 t = ((const float4*)x)[gid];
    f16x4 o = {(f16)t.x, (f16)t.y, (f16)t.z, (f16)t.w};
    *(f16x4*)&xh[(size_t)gid * 4] = o;
  } else {
    int widx = gid - XV;                 // 0 .. 1M-1
    int plane = widx >> 18;              // 256K float4 per weight plane
    int off = widx & ((1 << 18) - 1);
    const float* src = (plane == 0) ? wq : (plane == 1) ? wk : (plane == 2) ? wv : wo;
    float4 t = ((const float4*)src)[off];
    f16x4 o = {(f16)t.x, (f16)t.y, (f16)t.z, (f16)t.w};
    *(f16x4*)&wh[(size_t)widx * 4] = o;
  }
}

// ---------------------------------------------------------------------------
// Kernel 2/4: C[m][n] = sum_k A[m][k] * B[n][k]   (A:[M][K], B:[N][K] row-major)
// 128x128 tile, BK=64, 256 threads = 4 waves (2x2), each wave 64x64 via
// 4x4 frags of mfma_f32_16x16x32_f16. LDS XOR-swizzled (T2) to kill the
// 16-way bank conflict of a 128B-stride row-major tile.
// EPI=0: store fp16 to C (ldc given). EPI=1: store fp32 + bias.
// ---------------------------------------------------------------------------
template <int EPI>
__global__ __launch_bounds__(256) void gemm_bt(
    const f16* __restrict__ A, const f16* __restrict__ B, void* __restrict__ Cv,
    const float* __restrict__ bias, int K, int ldc) {
  __shared__ __align__(16) f16 As[128][64];
  __shared__ __align__(16) f16 Bs[128][64];
  const int m0 = blockIdx.y * 128;
  const int n0 = blockIdx.x * 128;
  const int t = threadIdx.x;
  const int wid = t >> 6, l = t & 63, g = l >> 4, c = l & 15;
  const int wm = (wid >> 1) * 64, wn = (wid & 1) * 64;

  f32x4 acc[4][4] = {};
  const int nkt = K >> 6;
  for (int kt = 0; kt < nkt; ++kt) {
    // -------- global -> LDS staging (swizzled writes) --------
#pragma unroll
    for (int i = 0; i < 4; ++i) {
      int chunk = t + i * 256;       // 0..1023
      int row = chunk >> 3;          // 0..127
      int c8 = chunk & 7;            // 16B chunk within row
      f16x8 va = *(const f16x8*)&A[(size_t)(m0 + row) * K + kt * 64 + c8 * 8];
      *(f16x8*)&As[row][(c8 ^ (row & 7)) * 8] = va;
      f16x8 vb = *(const f16x8*)&B[(size_t)(n0 + row) * K + kt * 64 + c8 * 8];
      *(f16x8*)&Bs[row][(c8 ^ (row & 7)) * 8] = vb;
    }
    __syncthreads();
    // -------- compute: 2 K-chunks of 32 --------
#pragma unroll
    for (int kc = 0; kc < 2; ++kc) {
      f16x8 af[4], bf[4];
#pragma unroll
      for (int mi = 0; mi < 4; ++mi) {
        int row = wm + mi * 16 + c;
        af[mi] = *(const f16x8*)&As[row][((kc * 4 + g) ^ (row & 7)) * 8];
      }
#pragma unroll
      for (int ni = 0; ni < 4; ++ni) {
        int row = wn + ni * 16 + c;
        bf[ni] = *(const f16x8*)&Bs[row][((kc * 4 + g) ^ (row & 7)) * 8];
      }
#pragma unroll
      for (int mi = 0; mi < 4; ++mi)
#pragma unroll
        for (int ni = 0; ni < 4; ++ni)
          acc[mi][ni] = __builtin_amdgcn_mfma_f32_16x16x32_f16(af[mi], bf[ni], acc[mi][ni], 0, 0, 0);
    }
    __syncthreads();
  }
  // -------- epilogue: D row = 4*g + r (within 16-block), col = c --------
#pragma unroll
  for (int mi = 0; mi < 4; ++mi) {
    int rowb = m0 + wm + mi * 16 + 4 * g;
#pragma unroll
    for (int ni = 0; ni < 4; ++ni) {
      int col = n0 + wn + ni * 16 + c;
#pragma unroll
      for (int r = 0; r < 4; ++r) {
        if (EPI == 0) {
          ((f16*)Cv)[(size_t)(rowb + r) * ldc + col] = (f16)acc[mi][ni][r];
        } else {
          ((float*)Cv)[(size_t)(rowb + r) * ldc + col] = acc[mi][ni][r] + bias[col];
        }
      }
    }
  }
}

// ---------------------------------------------------------------------------
// Kernel 3: flash attention. 1 wave per (b, h, 32 q-rows). KV tile = 16 keys.
// Swapped QK^T: S^T = mfma(Kfrag, Qfrag) so q-row = lane&15 -> softmax
// row-reduce is regs + shfl_xor(16) + shfl_xor(32).
// PV: mfma_f32_16x16x16f16(Vt_frag, P_frag, yacc): the S/P accumulator layout
// (key = 4*(l>>4)+r, qrow = l&15) IS the 16x16x16 B-operand layout.
// qkv layout: [4096][3072] fp16 (q | k | v planes of 1024 cols).
// ---------------------------------------------------------------------------
__global__ __launch_bounds__(256) void attn_kernel(const f16* __restrict__ qkv,
                                                   f16* __restrict__ yh) {
  const int wt = blockIdx.x * 4 + (threadIdx.x >> 6);  // 0..2047
  const int l = threadIdx.x & 63, g = l >> 4, c = l & 15;
  const int b = wt >> 10;          // 1024 wave-tasks per batch
  const int h = (wt >> 6) & 15;
  const int q0 = (wt & 63) * 32;
  const size_t ld = 3072;
  const f16* qp = qkv + (size_t)(b * 2048) * ld + h * 64;
  const f16* kp = qp + 1024;
  const f16* vp = qp + 2048;

  // Q fragments: lane holds Q[q0 + rb*16 + c][kc*32 + g*8 + 0..7]
  f16x8 qf[2][2];
#pragma unroll
  for (int rb = 0; rb < 2; ++rb)
#pragma unroll
    for (int kc = 0; kc < 2; ++kc)
      qf[rb][kc] = *(const f16x8*)&qp[(size_t)(q0 + rb * 16 + c) * ld + kc * 32 + g * 8];

  f32x4 yacc[2][4] = {};
  float mrow[2] = {-1e30f, -1e30f};
  float lrow[2] = {0.f, 0.f};
  const float scale = 0.03125f;  // 1/sqrt(1024)

  for (int key0 = 0; key0 < 2048; key0 += 16) {
    // K fragments: lane holds K[key0 + c][kc*32 + g*8 + 0..7]
    f16x8 kf[2];
#pragma unroll
    for (int kc = 0; kc < 2; ++kc)
      kf[kc] = *(const f16x8*)&kp[(size_t)(key0 + c) * ld + kc * 32 + g * 8];
    // V^T fragments (A-operand of 16x16x16): lane holds V[key0+4g+i][sb*16+c]
    f16x4 vf[4];
#pragma unroll
    for (int sb = 0; sb < 4; ++sb) {
      f16x4 tmp;
#pragma unroll
      for (int i = 0; i < 4; ++i)
        tmp[i] = vp[(size_t)(key0 + g * 4 + i) * ld + sb * 16 + c];
      vf[sb] = tmp;
    }
#pragma unroll
    for (int rb = 0; rb < 2; ++rb) {
      f32x4 s = {};
      s = __builtin_amdgcn_mfma_f32_16x16x32_f16(kf[0], qf[rb][0], s, 0, 0, 0);
      s = __builtin_amdgcn_mfma_f32_16x16x32_f16(kf[1], qf[rb][1], s, 0, 0, 0);
      float s0 = s[0] * scale, s1 = s[1] * scale, s2 = s[2] * scale, s3 = s[3] * scale;
      float tmax = fmaxf(fmaxf(s0, s1), fmaxf(s2, s3));
      tmax = fmaxf(tmax, __shfl_xor(tmax, 16, 64));
      tmax = fmaxf(tmax, __shfl_xor(tmax, 32, 64));
      float newm = fmaxf(mrow[rb], tmax);
      float p0 = __expf(s0 - newm), p1 = __expf(s1 - newm);
      float p2 = __expf(s2 - newm), p3 = __expf(s3 - newm);
      float psum = p0 + p1 + p2 + p3;
      psum += __shfl_xor(psum, 16, 64);
      psum += __shfl_xor(psum, 32, 64);
      float corr = __expf(mrow[rb] - newm);
      lrow[rb] = lrow[rb] * corr + psum;
      mrow[rb] = newm;
      f16x4 pf = {(f16)p0, (f16)p1, (f16)p2, (f16)p3};
#pragma unroll
      for (int sb = 0; sb < 4; ++sb) {
        yacc[rb][sb][0] *= corr;
        yacc[rb][sb][1] *= corr;
        yacc[rb][sb][2] *= corr;
        yacc[rb][sb][3] *= corr;
        yacc[rb][sb] = __builtin_amdgcn_mfma_f32_16x16x16f16(vf[sb], pf, yacc[rb][sb], 0, 0, 0);
      }
    }
  }
  // write y: lane holds Y[q0+rb*16+c][sb*16 + 4g + r]
#pragma unroll
  for (int rb = 0; rb < 2; ++rb) {
    float inv = 1.f / lrow[rb];
#pragma unroll
    for (int sb = 0; sb < 4; ++sb)
#pragma unroll
      for (int r = 0; r < 4; ++r)
        yh[(size_t)(b * 2048 + q0 + rb * 16 + c) * 1024 + h * 64 + sb * 16 + g * 4 + r] =
            (f16)(yacc[rb][sb][r] * inv);
  }
}

// ---------------------------------------------------------------------------
extern "C" void kernel_launch(void* const* d_in, const int* in_sizes, int n_in,
                              void* d_out, int out_size, void* d_ws, size_t ws_size,
                              hipStream_t stream) {
  (void)in_sizes; (void)n_in; (void)out_size; (void)ws_size;
  const float* x  = (const float*)d_in[0];
  const float* wq = (const float*)d_in[1];
  const float* wk = (const float*)d_in[2];
  const float* wv = (const float*)d_in[3];
  const float* wo = (const float*)d_in[4];
  const float* bo = (const float*)d_in[5];

  f16* xh   = (f16*)d_ws;                          // 4096*1024        (8 MB)
  f16* wh   = xh + (size_t)4096 * 1024;            // 4*1024*1024      (8 MB)
  f16* qkvh = wh + (size_t)4 * 1024 * 1024;        // 4096*3072        (24 MB)
  f16* yh   = qkvh + (size_t)4096 * 3072;          // 4096*1024        (8 MB)
  float* out = (float*)d_out;

  // 1) fp32 -> fp16 conversions (x + all four weight planes)
  cvt_kernel<<<8192, 256, 0, stream>>>(x, wq, wk, wv, wo, xh, wh);
  // 2) fused QKV projection: [4096x1024] @ [3072x1024]^T -> fp16 [4096][3072]
  gemm_bt<0><<<dim3(24, 32), 256, 0, stream>>>(xh, wh, qkvh, nullptr, 1024, 3072);
  // 3) flash attention -> y fp16 [4096][1024]
  attn_kernel<<<512, 256, 0, stream>>>(qkvh, yh);
  // 4) output projection + bias -> fp32 d_out
  gemm_bt<1><<<dim3(8, 32), 256, 0, stream>>>(yh, wh + (size_t)3 * 1024 * 1024, out, bo, 1024, 1024);
}

// Round 2
// 231.836 us; speedup vs baseline: 1.1619x; 1.1619x over previous
//
#include <hip/hip_runtime.h>
#include <hip/hip_fp16.h>

typedef _Float16 f16;
typedef __attribute__((ext_vector_type(4))) _Float16 f16x4;
typedef __attribute__((ext_vector_type(8))) _Float16 f16x8;
typedef __attribute__((ext_vector_type(4))) float f32x4;

// Async global->LDS, 16B per lane. LDS dest must be the WAVE-UNIFORM base
// (HW adds lane*16); global src is per-lane.
__device__ __forceinline__ void gload_lds16(const void* g, void* l) {
  __builtin_amdgcn_global_load_lds(
      (const __attribute__((address_space(1))) unsigned*)g,
      (__attribute__((address_space(3))) unsigned*)l, 16, 0, 0);
}

// ---------------------------------------------------------------------------
// Kernel 1: fp32 -> fp16 convert. Wq plane is prescaled by 1/sqrt(1024) so
// the attention score scale is free (folded into Q).
// ---------------------------------------------------------------------------
__global__ __launch_bounds__(256) void cvt_kernel(
    const float* __restrict__ x, const float* __restrict__ wq,
    const float* __restrict__ wk, const float* __restrict__ wv,
    const float* __restrict__ wo, f16* __restrict__ xh, f16* __restrict__ wh) {
  const int gid = blockIdx.x * 256 + threadIdx.x;   // float4 units
  const int XV = (4 * 1024 * 1024) / 4;
  if (gid < XV) {
    float4 t = ((const float4*)x)[gid];
    f16x4 o = {(f16)t.x, (f16)t.y, (f16)t.z, (f16)t.w};
    *(f16x4*)&xh[(size_t)gid * 4] = o;
  } else {
    int widx = gid - XV;
    int plane = widx >> 18;
    int off = widx & ((1 << 18) - 1);
    const float* src = (plane == 0) ? wq : (plane == 1) ? wk : (plane == 2) ? wv : wo;
    float4 t = ((const float4*)src)[off];
    if (plane == 0) {
      const float QS = 0.03125f;  // 1/sqrt(1024)
      t.x *= QS; t.y *= QS; t.z *= QS; t.w *= QS;
    }
    f16x4 o = {(f16)t.x, (f16)t.y, (f16)t.z, (f16)t.w};
    *(f16x4*)&wh[(size_t)widx * 4] = o;
  }
}

// ---------------------------------------------------------------------------
// Kernel 2/4: C[m][n] = sum_k A[m][k]*B[n][k]. m97 structure: 128x128 tile,
// BK=64, 4 waves, global_load_lds(16B) into LINEAR LDS (T2 null at 128²+2ph).
// ---------------------------------------------------------------------------
template <int EPI>
__global__ __launch_bounds__(256) void gemm_bt(
    const f16* __restrict__ A, const f16* __restrict__ B, void* __restrict__ Cv,
    const float* __restrict__ bias, int K, int ldc) {
  __shared__ __align__(16) f16 As[128][64];
  __shared__ __align__(16) f16 Bs[128][64];
  const int m0 = blockIdx.y * 128;
  const int n0 = blockIdx.x * 128;
  const int t = threadIdx.x;
  const int w = t >> 6, l = t & 63, g = l >> 4, c = l & 15;
  const int wm = (w >> 1) * 64, wn = (w & 1) * 64;

  f32x4 acc[4][4] = {};
  const int nkt = K >> 6;
  for (int kt = 0; kt < nkt; ++kt) {
    // ---- global -> LDS async staging, linear layout ----
#pragma unroll
    for (int i = 0; i < 4; ++i) {
      int ci = i * 256 + w * 64 + l;   // chunk index 0..1023
      int row = ci >> 3, c8 = ci & 7;
      gload_lds16(&A[(size_t)(m0 + row) * K + kt * 64 + c8 * 8],
                  (char*)&As[0][0] + (i * 256 + w * 64) * 16);
      gload_lds16(&B[(size_t)(n0 + row) * K + kt * 64 + c8 * 8],
                  (char*)&Bs[0][0] + (i * 256 + w * 64) * 16);
    }
    __syncthreads();
#pragma unroll
    for (int kc = 0; kc < 2; ++kc) {
      f16x8 af[4], bf[4];
#pragma unroll
      for (int mi = 0; mi < 4; ++mi)
        af[mi] = *(const f16x8*)&As[wm + mi * 16 + c][(kc * 4 + g) * 8];
#pragma unroll
      for (int ni = 0; ni < 4; ++ni)
        bf[ni] = *(const f16x8*)&Bs[wn + ni * 16 + c][(kc * 4 + g) * 8];
#pragma unroll
      for (int mi = 0; mi < 4; ++mi)
#pragma unroll
        for (int ni = 0; ni < 4; ++ni)
          acc[mi][ni] = __builtin_amdgcn_mfma_f32_16x16x32_f16(af[mi], bf[ni], acc[mi][ni], 0, 0, 0);
    }
    __syncthreads();
  }
#pragma unroll
  for (int mi = 0; mi < 4; ++mi) {
    int rowb = m0 + wm + mi * 16 + 4 * g;
#pragma unroll
    for (int ni = 0; ni < 4; ++ni) {
      int col = n0 + wn + ni * 16 + c;
#pragma unroll
      for (int r = 0; r < 4; ++r) {
        if (EPI == 0) {
          ((f16*)Cv)[(size_t)(rowb + r) * ldc + col] = (f16)acc[mi][ni][r];
        } else {
          ((float*)Cv)[(size_t)(rowb + r) * ldc + col] = acc[mi][ni][r] + bias[col];
        }
      }
    }
  }
}

// ---------------------------------------------------------------------------
// Kernel 3: flash attention v2. Block = 4 waves x 16 q-rows (QBLK=64),
// KVBLK=64 shared via LDS. K: global_load_lds + inverse-swizzled source
// (rule 21) -> conflict-free swizzled ds_read_b128. V: transposed into LDS
// via pair-packed ds_write_b32 -> PV fragments are ds_read_b64.
// Swapped QK^T (S^T = mfma(K,Q)) keeps softmax lane-local in q.
// Grid mapping pins each (b,h) to one XCD for L2 locality.
// ---------------------------------------------------------------------------
__global__ __launch_bounds__(256) void attn_kernel(const f16* __restrict__ qkv,
                                                   f16* __restrict__ yh) {
  __shared__ __align__(16) f16 Ks[64][64];
  __shared__ __align__(16) f16 Vt[64][64];
  const int t = threadIdx.x;
  const int w = t >> 6, l = t & 63, g = l >> 4, c = l & 15;
  const int bid = blockIdx.x;
  const int xcd = bid & 7, rest = bid >> 3;
  const int qc = rest & 31, bh = (rest >> 5) * 8 + xcd;
  const int b = bh >> 4, h = bh & 15;
  const int q0 = qc * 64 + w * 16;
  const size_t LD = 3072;
  const f16* qp = qkv + (size_t)(b * 2048) * LD + h * 64;
  const f16* kp = qp + 1024;
  const f16* vp = qp + 2048;

  // Q fragments: lane holds Q[q0+c][kc*32 + g*8 .. +8]  (Q pre-scaled by 1/32)
  f16x8 qf[2];
#pragma unroll
  for (int kc = 0; kc < 2; ++kc)
    qf[kc] = *(const f16x8*)&qp[(size_t)(q0 + c) * LD + kc * 32 + g * 8];

  const int rp = t & 31, vd0 = (t >> 5) * 8;  // V staging assignment

  f32x4 yacc[4] = {};
  float mrow = -1e30f, lrow = 0.f;

  for (int key0 = 0; key0 < 2048; key0 += 64) {
    // ---- stage K: linear LDS dest, inverse-swizzled global source ----
#pragma unroll
    for (int i = 0; i < 2; ++i) {
      int ci = i * 256 + w * 64 + l;               // 0..511
      int row = ci >> 3;
      int c8 = (ci & 7) ^ (row & 7);               // involutive source permute
      gload_lds16(&kp[(size_t)(key0 + row) * LD + c8 * 8],
                  (char*)&Ks[0][0] + (i * 256 + w * 64) * 16);
    }
    // ---- stage V transposed: thread owns rows (2rp,2rp+1) x dims [vd0,vd0+8) ----
    f16x8 va = *(const f16x8*)&vp[(size_t)(key0 + 2 * rp) * LD + vd0];
    f16x8 vb = *(const f16x8*)&vp[(size_t)(key0 + 2 * rp + 1) * LD + vd0];
#pragma unroll
    for (int j = 0; j < 8; ++j) {
      int dd = vd0 + j;
      union { f16 h2[2]; unsigned u; } pk;
      pk.h2[0] = va[j]; pk.h2[1] = vb[j];
      // Vt[dd][2rp..2rp+1], row-swizzled at 16B units
      int off = dd * 128 + (((rp >> 2) ^ (dd & 7)) * 16) + 4 * (rp & 3);
      *(unsigned*)((char*)&Vt[0][0] + off) = pk.u;
    }
    __syncthreads();

    // ---- QK^T: S^T accum, keys kb*16+4g+r, q=c ----
    f32x4 s[4];
#pragma unroll
    for (int kb = 0; kb < 4; ++kb) {
      f32x4 acc = {};
#pragma unroll
      for (int kc = 0; kc < 2; ++kc) {
        int row = kb * 16 + c;
        f16x8 kf = *(const f16x8*)((char*)&Ks[0][0] + row * 128 +
                                   (((kc * 4 + g) ^ (row & 7)) * 16));
        acc = __builtin_amdgcn_mfma_f32_16x16x32_f16(kf, qf[kc], acc, 0, 0, 0);
      }
      s[kb] = acc;
    }
    // ---- one softmax pass per 64 keys ----
    float tmax = -1e30f;
#pragma unroll
    for (int kb = 0; kb < 4; ++kb)
#pragma unroll
      for (int r = 0; r < 4; ++r) tmax = fmaxf(tmax, s[kb][r]);
    tmax = fmaxf(tmax, __shfl_xor(tmax, 16, 64));
    tmax = fmaxf(tmax, __shfl_xor(tmax, 32, 64));
    float newm = fmaxf(mrow, tmax);
    float corr = __expf(mrow - newm);
    float psum = 0.f;
    f16x4 pf[4];
#pragma unroll
    for (int kb = 0; kb < 4; ++kb)
#pragma unroll
      for (int r = 0; r < 4; ++r) {
        float p = __expf(s[kb][r] - newm);
        psum += p;
        pf[kb][r] = (f16)p;
      }
    psum += __shfl_xor(psum, 16, 64);
    psum += __shfl_xor(psum, 32, 64);
    lrow = lrow * corr + psum;
    mrow = newm;
#pragma unroll
    for (int sb = 0; sb < 4; ++sb) {
      yacc[sb][0] *= corr; yacc[sb][1] *= corr;
      yacc[sb][2] *= corr; yacc[sb][3] *= corr;
    }
    // ---- PV: yacc[sb] += V^T[sb-block] . P ----
#pragma unroll
    for (int kb = 0; kb < 4; ++kb)
#pragma unroll
      for (int sb = 0; sb < 4; ++sb) {
        int row = sb * 16 + c;
        f16x4 vf = *(const f16x4*)((char*)&Vt[0][0] + row * 128 +
                                   (((2 * kb + (g >> 1)) ^ (row & 7)) * 16) + 8 * (g & 1));
        yacc[sb] = __builtin_amdgcn_mfma_f32_16x16x16f16(vf, pf[kb], yacc[sb], 0, 0, 0);
      }
    __syncthreads();
  }
  // ---- write Y: lane holds Y[q0+c][sb*16+4g+r], packed f16x4 stores ----
  const float inv = 1.f / lrow;
#pragma unroll
  for (int sb = 0; sb < 4; ++sb) {
    f16x4 o = {(f16)(yacc[sb][0] * inv), (f16)(yacc[sb][1] * inv),
               (f16)(yacc[sb][2] * inv), (f16)(yacc[sb][3] * inv)};
    *(f16x4*)&yh[(size_t)(b * 2048 + q0 + c) * 1024 + h * 64 + sb * 16 + 4 * g] = o;
  }
}

// ---------------------------------------------------------------------------
extern "C" void kernel_launch(void* const* d_in, const int* in_sizes, int n_in,
                              void* d_out, int out_size, void* d_ws, size_t ws_size,
                              hipStream_t stream) {
  (void)in_sizes; (void)n_in; (void)out_size; (void)ws_size;
  const float* x  = (const float*)d_in[0];
  const float* wq = (const float*)d_in[1];
  const float* wk = (const float*)d_in[2];
  const float* wv = (const float*)d_in[3];
  const float* wo = (const float*)d_in[4];
  const float* bo = (const float*)d_in[5];

  f16* xh   = (f16*)d_ws;                          // 4096*1024
  f16* wh   = xh + (size_t)4096 * 1024;            // 4*1024*1024
  f16* qkvh = wh + (size_t)4 * 1024 * 1024;        // 4096*3072
  f16* yh   = qkvh + (size_t)4096 * 3072;          // 4096*1024
  float* out = (float*)d_out;

  cvt_kernel<<<8192, 256, 0, stream>>>(x, wq, wk, wv, wo, xh, wh);
  gemm_bt<0><<<dim3(24, 32), 256, 0, stream>>>(xh, wh, qkvh, nullptr, 1024, 3072);
  attn_kernel<<<1024, 256, 0, stream>>>(qkvh, yh);
  gemm_bt<1><<<dim3(8, 32), 256, 0, stream>>>(yh, wh + (size_t)3 * 1024 * 1024, out, bo, 1024, 1024);
}

// Round 3
// 223.120 us; speedup vs baseline: 1.2073x; 1.0391x over previous
//
#include <hip/hip_runtime.h>
#include <hip/hip_fp16.h>

typedef _Float16 f16;
typedef __attribute__((ext_vector_type(4))) _Float16 f16x4;
typedef __attribute__((ext_vector_type(8))) _Float16 f16x8;
typedef __attribute__((ext_vector_type(4))) float f32x4;

// Async global->LDS, 16B per lane. LDS dest is WAVE-UNIFORM base (+lane*16).
__device__ __forceinline__ void gload_lds16(const void* g, void* l) {
  __builtin_amdgcn_global_load_lds(
      (const __attribute__((address_space(1))) unsigned*)g,
      (__attribute__((address_space(3))) unsigned*)l, 16, 0, 0);
}

// ---------------------------------------------------------------------------
// Kernel 1: fp32 -> fp16 convert. Wq prescaled by log2(e)/sqrt(1024): folds
// both the attention score scale AND the exp->exp2 conversion into Q.
// ---------------------------------------------------------------------------
__global__ __launch_bounds__(256) void cvt_kernel(
    const float* __restrict__ x, const float* __restrict__ wq,
    const float* __restrict__ wk, const float* __restrict__ wv,
    const float* __restrict__ wo, f16* __restrict__ xh, f16* __restrict__ wh) {
  const int gid = blockIdx.x * 256 + threadIdx.x;   // float4 units
  const int XV = (4 * 1024 * 1024) / 4;
  if (gid < XV) {
    float4 t = ((const float4*)x)[gid];
    f16x4 o = {(f16)t.x, (f16)t.y, (f16)t.z, (f16)t.w};
    *(f16x4*)&xh[(size_t)gid * 4] = o;
  } else {
    int widx = gid - XV;
    int plane = widx >> 18;
    int off = widx & ((1 << 18) - 1);
    const float* src = (plane == 0) ? wq : (plane == 1) ? wk : (plane == 2) ? wv : wo;
    float4 t = ((const float4*)src)[off];
    if (plane == 0) {
      const float QS = 0.045084547f;  // log2(e) / 32
      t.x *= QS; t.y *= QS; t.z *= QS; t.w *= QS;
    }
    f16x4 o = {(f16)t.x, (f16)t.y, (f16)t.z, (f16)t.w};
    *(f16x4*)&wh[(size_t)widx * 4] = o;
  }
}

// ---------------------------------------------------------------------------
// Kernel 2/4: C[m][n] = sum_k A[m][k]*B[n][k]. m97 structure (unchanged).
// ---------------------------------------------------------------------------
template <int EPI>
__global__ __launch_bounds__(256) void gemm_bt(
    const f16* __restrict__ A, const f16* __restrict__ B, void* __restrict__ Cv,
    const float* __restrict__ bias, int K, int ldc) {
  __shared__ __align__(16) f16 As[128][64];
  __shared__ __align__(16) f16 Bs[128][64];
  const int m0 = blockIdx.y * 128;
  const int n0 = blockIdx.x * 128;
  const int t = threadIdx.x;
  const int w = t >> 6, l = t & 63, g = l >> 4, c = l & 15;
  const int wm = (w >> 1) * 64, wn = (w & 1) * 64;

  f32x4 acc[4][4] = {};
  const int nkt = K >> 6;
  for (int kt = 0; kt < nkt; ++kt) {
#pragma unroll
    for (int i = 0; i < 4; ++i) {
      int ci = i * 256 + w * 64 + l;
      int row = ci >> 3, c8 = ci & 7;
      gload_lds16(&A[(size_t)(m0 + row) * K + kt * 64 + c8 * 8],
                  (char*)&As[0][0] + (i * 256 + w * 64) * 16);
      gload_lds16(&B[(size_t)(n0 + row) * K + kt * 64 + c8 * 8],
                  (char*)&Bs[0][0] + (i * 256 + w * 64) * 16);
    }
    __syncthreads();
#pragma unroll
    for (int kc = 0; kc < 2; ++kc) {
      f16x8 af[4], bf[4];
#pragma unroll
      for (int mi = 0; mi < 4; ++mi)
        af[mi] = *(const f16x8*)&As[wm + mi * 16 + c][(kc * 4 + g) * 8];
#pragma unroll
      for (int ni = 0; ni < 4; ++ni)
        bf[ni] = *(const f16x8*)&Bs[wn + ni * 16 + c][(kc * 4 + g) * 8];
#pragma unroll
      for (int mi = 0; mi < 4; ++mi)
#pragma unroll
        for (int ni = 0; ni < 4; ++ni)
          acc[mi][ni] = __builtin_amdgcn_mfma_f32_16x16x32_f16(af[mi], bf[ni], acc[mi][ni], 0, 0, 0);
    }
    __syncthreads();
  }
#pragma unroll
  for (int mi = 0; mi < 4; ++mi) {
    int rowb = m0 + wm + mi * 16 + 4 * g;
#pragma unroll
    for (int ni = 0; ni < 4; ++ni) {
      int col = n0 + wn + ni * 16 + c;
#pragma unroll
      for (int r = 0; r < 4; ++r) {
        if (EPI == 0) {
          ((f16*)Cv)[(size_t)(rowb + r) * ldc + col] = (f16)acc[mi][ni][r];
        } else {
          ((float*)Cv)[(size_t)(rowb + r) * ldc + col] = acc[mi][ni][r] + bias[col];
        }
      }
    }
  }
}

// ---------------------------------------------------------------------------
// Kernel 3: flash attention v3. Block = 4 waves x 32 q-rows (QBLK=128),
// KVBLK=64, double-buffered LDS (2-phase pipeline + async V stage).
// Swapped QK^T; exp2 softmax (scale folded into Q); defer-max (THR=8).
// ---------------------------------------------------------------------------
__global__ __launch_bounds__(256) void attn_kernel(const f16* __restrict__ qkv,
                                                   f16* __restrict__ yh) {
  __shared__ __align__(16) f16 Ks[2][64][64];
  __shared__ __align__(16) f16 Vt[2][64][64];
  const int t = threadIdx.x;
  const int w = t >> 6, l = t & 63, g = l >> 4, c = l & 15;
  const int bid = blockIdx.x;                 // 512 blocks
  const int xcd = bid & 7, rest = bid >> 3;
  const int qc = rest & 15, bh = (rest >> 4) * 8 + xcd;
  const int b = bh >> 4, h = bh & 15;
  const int q0 = qc * 128 + w * 32;
  const size_t LD = 3072;
  const f16* qp = qkv + (size_t)(b * 2048) * LD + h * 64;
  const f16* kp = qp + 1024;
  const f16* vp = qp + 2048;
  const int rp = t & 31, vd0 = (t >> 5) * 8;  // V staging assignment

  // Q fragments: lane holds Q[q0 + rb*16 + c][kc*32 + g*8 ..+8] (pre-scaled)
  f16x8 qf[2][2];
#pragma unroll
  for (int rb = 0; rb < 2; ++rb)
#pragma unroll
    for (int kc = 0; kc < 2; ++kc)
      qf[rb][kc] = *(const f16x8*)&qp[(size_t)(q0 + rb * 16 + c) * LD + kc * 32 + g * 8];

  auto stageK = [&](int buf, int key0) {
#pragma unroll
    for (int i = 0; i < 2; ++i) {
      int ci = i * 256 + w * 64 + l;
      int row = ci >> 3;
      int c8 = (ci & 7) ^ (row & 7);          // involutive source permute
      gload_lds16(&kp[(size_t)(key0 + row) * LD + c8 * 8],
                  (char*)&Ks[buf][0][0] + (i * 256 + w * 64) * 16);
    }
  };
  auto writeV = [&](int buf, f16x8 xa, f16x8 xb) {
#pragma unroll
    for (int j = 0; j < 8; ++j) {
      int dd = vd0 + j;
      union { f16 h2[2]; unsigned u; } pk;
      pk.h2[0] = xa[j]; pk.h2[1] = xb[j];
      int off = dd * 128 + (((rp >> 2) ^ (dd & 7)) * 16) + 4 * (rp & 3);
      *(unsigned*)((char*)&Vt[buf][0][0] + off) = pk.u;
    }
  };

  f32x4 yacc[2][4] = {};
  float m[2] = {-1e30f, -1e30f};
  float lr[2] = {0.f, 0.f};

  // prologue: stage tile 0
  stageK(0, 0);
  {
    f16x8 va = *(const f16x8*)&vp[(size_t)(2 * rp) * LD + vd0];
    f16x8 vb = *(const f16x8*)&vp[(size_t)(2 * rp + 1) * LD + vd0];
    writeV(0, va, vb);
  }
  __syncthreads();

  int cur = 0;
  for (int kt = 0; kt < 32; ++kt) {
    const bool hn = (kt < 31);
    f16x8 nva, nvb;
    if (hn) {                                  // issue next-tile loads early
      int key0n = (kt + 1) * 64;
      stageK(cur ^ 1, key0n);
      nva = *(const f16x8*)&vp[(size_t)(key0n + 2 * rp) * LD + vd0];
      nvb = *(const f16x8*)&vp[(size_t)(key0n + 2 * rp + 1) * LD + vd0];
    }
    // ---- QK^T: S^T[key][q], K-frags amortized over both q-blocks ----
    f32x4 s[2][4];
    __builtin_amdgcn_s_setprio(1);
#pragma unroll
    for (int kb = 0; kb < 4; ++kb) {
      int row = kb * 16 + c;
      f16x8 kf0 = *(const f16x8*)((char*)&Ks[cur][0][0] + row * 128 + ((g ^ (row & 7)) * 16));
      f16x8 kf1 = *(const f16x8*)((char*)&Ks[cur][0][0] + row * 128 + (((4 + g) ^ (row & 7)) * 16));
#pragma unroll
      for (int rb = 0; rb < 2; ++rb) {
        f32x4 acc = {};
        acc = __builtin_amdgcn_mfma_f32_16x16x32_f16(kf0, qf[rb][0], acc, 0, 0, 0);
        acc = __builtin_amdgcn_mfma_f32_16x16x32_f16(kf1, qf[rb][1], acc, 0, 0, 0);
        s[rb][kb] = acc;
      }
    }
    __builtin_amdgcn_s_setprio(0);
    // ---- softmax (base-2, per q-block), defer-max ----
    float pmax[2];
#pragma unroll
    for (int rb = 0; rb < 2; ++rb) {
      float tm = s[rb][0][0];
#pragma unroll
      for (int kb = 0; kb < 4; ++kb)
#pragma unroll
        for (int r = 0; r < 4; ++r) tm = fmaxf(tm, s[rb][kb][r]);
      tm = fmaxf(tm, __shfl_xor(tm, 16, 64));
      tm = fmaxf(tm, __shfl_xor(tm, 32, 64));
      pmax[rb] = tm;
    }
    bool need = (pmax[0] > m[0] + 8.f) || (pmax[1] > m[1] + 8.f);
    if (__any(need)) {
#pragma unroll
      for (int rb = 0; rb < 2; ++rb) {
        float nm = fmaxf(m[rb], pmax[rb]);
        float corr = __builtin_amdgcn_exp2f(m[rb] - nm);
        lr[rb] *= corr;
#pragma unroll
        for (int sb = 0; sb < 4; ++sb) {
          yacc[rb][sb][0] *= corr; yacc[rb][sb][1] *= corr;
          yacc[rb][sb][2] *= corr; yacc[rb][sb][3] *= corr;
        }
        m[rb] = nm;
      }
    }
    f16x4 pf[2][4];
#pragma unroll
    for (int rb = 0; rb < 2; ++rb) {
      float ps = 0.f;
#pragma unroll
      for (int kb = 0; kb < 4; ++kb)
#pragma unroll
        for (int r = 0; r < 4; ++r) {
          float p = __builtin_amdgcn_exp2f(s[rb][kb][r] - m[rb]);
          ps += p;
          pf[rb][kb][r] = (f16)p;
        }
      ps += __shfl_xor(ps, 16, 64);
      ps += __shfl_xor(ps, 32, 64);
      lr[rb] += ps;
    }
    // ---- PV: V-frags amortized over both q-blocks ----
    __builtin_amdgcn_s_setprio(1);
#pragma unroll
    for (int kb = 0; kb < 4; ++kb)
#pragma unroll
      for (int sb = 0; sb < 4; ++sb) {
        int row = sb * 16 + c;
        f16x4 vf = *(const f16x4*)((char*)&Vt[cur][0][0] + row * 128 +
                                   (((2 * kb + (g >> 1)) ^ (row & 7)) * 16) + 8 * (g & 1));
        yacc[0][sb] = __builtin_amdgcn_mfma_f32_16x16x16f16(vf, pf[0][kb], yacc[0][sb], 0, 0, 0);
        yacc[1][sb] = __builtin_amdgcn_mfma_f32_16x16x16f16(vf, pf[1][kb], yacc[1][sb], 0, 0, 0);
      }
    __builtin_amdgcn_s_setprio(0);
    if (hn) writeV(cur ^ 1, nva, nvb);         // vmcnt wait lands here, hidden
    __syncthreads();
    cur ^= 1;
  }
  // ---- write Y ----
#pragma unroll
  for (int rb = 0; rb < 2; ++rb) {
    float inv = 1.f / lr[rb];
#pragma unroll
    for (int sb = 0; sb < 4; ++sb) {
      f16x4 o = {(f16)(yacc[rb][sb][0] * inv), (f16)(yacc[rb][sb][1] * inv),
                 (f16)(yacc[rb][sb][2] * inv), (f16)(yacc[rb][sb][3] * inv)};
      *(f16x4*)&yh[(size_t)(b * 2048 + q0 + rb * 16 + c) * 1024 + h * 64 + sb * 16 + 4 * g] = o;
    }
  }
}

// ---------------------------------------------------------------------------
extern "C" void kernel_launch(void* const* d_in, const int* in_sizes, int n_in,
                              void* d_out, int out_size, void* d_ws, size_t ws_size,
                              hipStream_t stream) {
  (void)in_sizes; (void)n_in; (void)out_size; (void)ws_size;
  const float* x  = (const float*)d_in[0];
  const float* wq = (const float*)d_in[1];
  const float* wk = (const float*)d_in[2];
  const float* wv = (const float*)d_in[3];
  const float* wo = (const float*)d_in[4];
  const float* bo = (const float*)d_in[5];

  f16* xh   = (f16*)d_ws;
  f16* wh   = xh + (size_t)4096 * 1024;
  f16* qkvh = wh + (size_t)4 * 1024 * 1024;
  f16* yh   = qkvh + (size_t)4096 * 3072;
  float* out = (float*)d_out;

  cvt_kernel<<<8192, 256, 0, stream>>>(x, wq, wk, wv, wo, xh, wh);
  gemm_bt<0><<<dim3(24, 32), 256, 0, stream>>>(xh, wh, qkvh, nullptr, 1024, 3072);
  attn_kernel<<<512, 256, 0, stream>>>(qkvh, yh);
  gemm_bt<1><<<dim3(8, 32), 256, 0, stream>>>(yh, wh + (size_t)3 * 1024 * 1024, out, bo, 1024, 1024);
}